// Round 3
// baseline (322.338 us; speedup 1.0000x reference)
//
#include <hip/hip_runtime.h>

// GroupSort over channel pairs (B=32, C=512, H=56, W=56 fp32):
//   out[:,2k]   = xe - relu(xe - xo)   (ref-exact arithmetic)
//   out[:,2k+1] = xo + relu(xe - xo)
// Channel plane = 3136 floats = 784 float4s; pair channels are adjacent planes.
// Pure streaming, 411 MB total -> HBM-bound, ~70 us floor at ~5.8 TB/s mixed.
//
// R2: 4 float4-pairs per thread (wave-strided, each ld/st instruction is a
// contiguous 1 KiB wave access) -> 8 outstanding 16B loads/thread for MLP,
// 4x fewer index computations and wave ramp/drain events.

#define HW4 784u                     // float4s per channel plane
#define TOTAL4 6422528u              // 32 * 256 * 784 even-half float4s
#define PER_BLOCK 1024u              // 256 threads * 4 float4s
#define NBLOCKS (TOTAL4 / PER_BLOCK) // 6272, exact

typedef float v4 __attribute__((ext_vector_type(4)));

__global__ __launch_bounds__(256) void groupsort_kernel(
    const v4* __restrict__ in, v4* __restrict__ out) {
    const unsigned int i0 = blockIdx.x * PER_BLOCK + threadIdx.x;

    unsigned int base[4];
#pragma unroll
    for (int k = 0; k < 4; ++k) {
        unsigned int i = i0 + k * 256u;          // grid exact, no guard
        unsigned int pair = i / HW4;             // magic-mul
        unsigned int hw   = i - pair * HW4;
        base[k] = pair * (2u * HW4) + hw;        // even-plane float4 index
    }

    v4 e[4], o[4];
#pragma unroll
    for (int k = 0; k < 4; ++k) e[k] = __builtin_nontemporal_load(in + base[k]);
#pragma unroll
    for (int k = 0; k < 4; ++k) o[k] = __builtin_nontemporal_load(in + base[k] + HW4);

    v4 eo[4], oo[4];
#pragma unroll
    for (int k = 0; k < 4; ++k) {
        v4 d = e[k] - o[k];
        v4 z;
        z.x = fmaxf(d.x, 0.0f);
        z.y = fmaxf(d.y, 0.0f);
        z.z = fmaxf(d.z, 0.0f);
        z.w = fmaxf(d.w, 0.0f);
        eo[k] = e[k] - z;
        oo[k] = o[k] + z;
    }

#pragma unroll
    for (int k = 0; k < 4; ++k) __builtin_nontemporal_store(eo[k], out + base[k]);
#pragma unroll
    for (int k = 0; k < 4; ++k) __builtin_nontemporal_store(oo[k], out + base[k] + HW4);
}

extern "C" void kernel_launch(void* const* d_in, const int* in_sizes, int n_in,
                              void* d_out, int out_size, void* d_ws, size_t ws_size,
                              hipStream_t stream) {
    const v4* x = (const v4*)d_in[0];
    v4* out = (v4*)d_out;
    groupsort_kernel<<<NBLOCKS, 256, 0, stream>>>(x, out);
}